// Round 3
// baseline (182.487 us; speedup 1.0000x reference)
//
#include <hip/hip_runtime.h>

// MoE: out[b,:] = sum_e softmax(gate(x))[b,e] * (W3_e^T @ relu(W2_e^T @ relu(W1_e^T @ x_b + b1) + b2) + b3)
// Tokens-as-N MFMA. L1 uses 16x16x16 f16 (K=7 useful, k=4q+j). L2/L3/gate-L2 use 16x16x32 f16
// with K-permutation pi(q*8+j)=q*4+(j&3)+16*(j>>2) so C/D layout == next layer's B layout
// in-lane (HW-verified across R2-R10: absmax 0.0156).
// R11: WAVE-PAIR design, sized to fit the 128-VGPR cap the allocator enforced in R9/R10
//      (waves_per_eu(2,2) was seen -- SGPR changed -- but VGPR stayed 128 and spill traffic
//      was byte-identical; ~100 regs spilled killed both rounds). EPW=4: wave h of a pair
//      runs experts 4h..4h+3 (~88 weight VGPRs + ~35 misc ~= 120 <= 128, zero spills by
//      construction). Y rows m=(e,o): wave0 rows 0-7, wave1 rows 8-15 (b3 C-init masked to
//      owned quads). Combine: h1 sends one float2/token via LDS, h0 adds + scales rs +
//      stores; parity double-buffer, ONE barrier/tile. Gate redundancy 2x (was 4x in R8).
//      1024 blocks x 4 waves = exact residency at 4 waves/SIMD (pinned waves_per_eu(4,4)).

typedef _Float16 half2_t __attribute__((ext_vector_type(2)));
typedef _Float16 half4_t __attribute__((ext_vector_type(4)));
typedef _Float16 half8_t __attribute__((ext_vector_type(8)));
typedef __fp16   fp16v2  __attribute__((ext_vector_type(2)));
typedef float  float4_t __attribute__((ext_vector_type(4)));
typedef float  float2_t __attribute__((ext_vector_type(2)));
typedef int    int2_t   __attribute__((ext_vector_type(2)));
typedef int    int4_t   __attribute__((ext_vector_type(4)));

#define MFMA_K32(A, B, C) __builtin_amdgcn_mfma_f32_16x16x32_f16((A), (B), (C), 0, 0, 0)
#define MFMA_K16(A, B, C) __builtin_amdgcn_mfma_f32_16x16x16f16((A), (B), (C), 0, 0, 0)

static constexpr int E_ = 8, DIN_ = 6, H_ = 32, EPW_ = 4;   // experts per wave (pair = 8)

union H8U { half2_t h2[4]; half8_t h8; int4_t i4; };
union H4U { half2_t h2[2]; half4_t h4; int2_t i2; };
union HI  { half2_t h; int i; };
union PKU { fp16v2 p; half2_t h; };

__device__ __forceinline__ half2_t pkrtz(float a, float b) {
    PKU u; u.p = __builtin_amdgcn_cvt_pkrtz(a, b);
    return u.h;
}

__device__ __forceinline__ half2_t relu2(half2_t v) {
    const half2_t z = {(_Float16)0.0f, (_Float16)0.0f};
    return __builtin_elementwise_max(v, z);
}

__global__ __launch_bounds__(256)
__attribute__((amdgpu_waves_per_eu(4, 4)))
void moe_kernel(
    const float* __restrict__ x,  const float* __restrict__ W1, const float* __restrict__ b1,
    const float* __restrict__ W2, const float* __restrict__ b2, const float* __restrict__ W3,
    const float* __restrict__ b3, const float* __restrict__ Wg1, const float* __restrict__ bg1,
    const float* __restrict__ Wg2, const float* __restrict__ bg2,
    float* __restrict__ out, int nTiles, int tilesPerPair)
{
    const int tid  = threadIdx.x;
    const int lane = tid & 63;
    const int t    = lane & 15;   // token slot
    const int q    = lane >> 4;   // K-quad / row-quad
    const int wv   = tid >> 6;    // wave in block 0..3
    const int pr   = wv >> 1;     // pair in block 0..1
    const int h    = wv & 1;      // half of pair: experts 4h..4h+3
    const int eb   = h * EPW_;

    __shared__ float2_t cb[2][2][16];   // parity x pair x token, 512 B

    const float L2E = 1.44269504f;

    // ---- gate L1 A-fragments (K=16, k=4q+j; slots 0..5 = x features, 6 = bias-as-1.0)
    H4U G1[2];
    #pragma unroll
    for (int f = 0; f < 2; ++f) {
        float v0 = 0.f, v1 = 0.f, v2 = 0.f, v3 = 0.f;
        if (q == 0) {
            v0 = Wg1[0 * H_ + f * 16 + t]; v1 = Wg1[1 * H_ + f * 16 + t];
            v2 = Wg1[2 * H_ + f * 16 + t]; v3 = Wg1[3 * H_ + f * 16 + t];
        } else if (q == 1) {
            v0 = Wg1[4 * H_ + f * 16 + t]; v1 = Wg1[5 * H_ + f * 16 + t];
            v2 = bg1[f * 16 + t];          v3 = 0.f;
        }
        G1[f].h2[0] = pkrtz(v0, v1); G1[f].h2[1] = pkrtz(v2, v3);
    }
    // ---- gate L2 A-fragment (K=32, pi layout), pre-scaled by log2(e) so logits are exp2-ready
    H8U G2;
    #pragma unroll
    for (int p = 0; p < 4; ++p) {
        int c0 = ((p >> 1) << 4) + q * 4 + ((p & 1) << 1);
        float v0 = (t < E_) ? Wg2[c0 * E_ + t] * L2E : 0.f;
        float v1 = (t < E_) ? Wg2[(c0 + 1) * E_ + t] * L2E : 0.f;
        G2.h2[p] = pkrtz(v0, v1);
    }

    // ---- this wave's 4 experts (global ge = eb+e): L1 (K16), L2 (K32 pi), L3 (K32 pi,
    //      block-diag rows m=(ge,o)), b2 pairs
    H4U W1F[EPW_][2];
    H8U W2F[EPW_][2], W3F[EPW_], B2R[EPW_];
    #pragma unroll
    for (int e = 0; e < EPW_; ++e) {
        const int ge = eb + e;
        #pragma unroll
        for (int f = 0; f < 2; ++f) {
            float v0 = 0.f, v1 = 0.f, v2 = 0.f, v3 = 0.f;
            const float* We = W1 + (size_t)ge * DIN_ * H_ + f * 16 + t;
            if (q == 0)      { v0 = We[0 * H_]; v1 = We[1 * H_]; v2 = We[2 * H_]; v3 = We[3 * H_]; }
            else if (q == 1) { v0 = We[4 * H_]; v1 = We[5 * H_]; v2 = b1[ge * H_ + f * 16 + t]; }
            W1F[e][f].h2[0] = pkrtz(v0, v1); W1F[e][f].h2[1] = pkrtz(v2, v3);
        }
        #pragma unroll
        for (int p = 0; p < 4; ++p) {
            int c0 = ((p >> 1) << 4) + q * 4 + ((p & 1) << 1);
            W2F[e][0].h2[p] = pkrtz(W2[(ge * H_ + c0) * H_ + 0  + t], W2[(ge * H_ + c0 + 1) * H_ + 0  + t]);
            W2F[e][1].h2[p] = pkrtz(W2[(ge * H_ + c0) * H_ + 16 + t], W2[(ge * H_ + c0 + 1) * H_ + 16 + t]);
            B2R[e].h2[p]    = pkrtz(b2[ge * H_ + c0], b2[ge * H_ + c0 + 1]);
            float v0 = 0.f, v1 = 0.f;
            if ((t >> 1) == ge) {     // Y rows m=(ge,o): this expert's rows only
                v0 = W3[(ge * H_ + c0) * 2 + (t & 1)];
                v1 = W3[(ge * H_ + c0 + 1) * 2 + (t & 1)];
            }
            W3F[e].h2[p] = pkrtz(v0, v1);
        }
    }

    // ---- persistent C-inits: bg2 (log2-domain) for the gate; b3 only on OWNED quads
    //      (wave h owns Y rows 8h..8h+7 = quads 2h..2h+1; other quads must reduce to 0)
    float4_t bg2F, b3F;
    #pragma unroll
    for (int r = 0; r < 4; ++r) {
        int m = q * 4 + r;
        bg2F[r] = (m < E_) ? bg2[m] * L2E : 0.f;
        b3F[r]  = ((q >> 1) == h) ? b3[m] : 0.f;
    }
    const float4_t zero4 = {0.f, 0.f, 0.f, 0.f};

    // gate pull: lane(q,t) fetches ex[t,2q],ex[t,2q+1] from lane (q>>1)*16+t
    const int gsrc = ((((q >> 1) << 4) | t) << 2);

    const int tile0 = (blockIdx.x * 2 + pr) * tilesPerPair;

    // ---- per-lane x source (loop-invariant): quad0 reads x[t][0..3]; quads>=1 read x[t][4..5]
    const int xo1 = (q == 0) ? 0 : 4;
    const int xo2 = (q == 0) ? 2 : 4;
    const float* xq = x + ((size_t)tile0 * 16 + t) * DIN_;
    float2_t la = {0.f, 0.f}, lb = {0.f, 0.f};
    if (tile0 < nTiles) {
        la = *(const float2_t*)(xq + xo1);
        lb = *(const float2_t*)(xq + xo2);
    }

    HI onei; onei.h = pkrtz(1.f, 0.f);
    const bool isq0 = (q == 0);

    for (int it = 0; it < tilesPerPair; ++it) {
        const int tile = tile0 + it;
        const bool active = (tile < nTiles);    // uniform per pair; barrier stays uniform

        float p0 = 0.f, p1 = 0.f, rs = 0.f;
        if (active) {
            // ---- x B-fragment (K=16): q0:(x0..x3) q1:(x4,x5,1,dc) q2/q3: dc (A=0 there)
            H4U ux;
            ux.h2[0] = pkrtz(la[0], la[1]);
            HI hb; hb.h = pkrtz(lb[0], lb[1]);
            HI se; se.i = isq0 ? hb.i : onei.i;
            ux.h2[1] = se.h;
            const half4_t xB = ux.h4;

            // ---- prefetch next tile's x
            if ((it + 1) < tilesPerPair && (tile + 1) < nTiles) {
                const float* xn = xq + (size_t)(it + 1) * 16 * DIN_;
                la = *(const float2_t*)(xn + xo1);
                lb = *(const float2_t*)(xn + xo2);
            }

            // ---- gate (2x redundant: once per wave of the pair; logits in log2 domain)
            float4_t hgLo = MFMA_K16(G1[0].h4, xB, zero4);
            float4_t hgHi = MFMA_K16(G1[1].h4, xB, zero4);
            H8U uh;
            uh.h2[0] = relu2(pkrtz(hgLo[0], hgLo[1]));
            uh.h2[1] = relu2(pkrtz(hgLo[2], hgLo[3]));
            uh.h2[2] = relu2(pkrtz(hgHi[0], hgHi[1]));
            uh.h2[3] = relu2(pkrtz(hgHi[2], hgHi[3]));
            float4_t gl = MFMA_K32(G2.h8, uh.h8, bg2F);

            // ---- softmax over 8 experts, no max-sub, normalization deferred to the store
            float ex0 = __builtin_amdgcn_exp2f(gl[0]);
            float ex1 = __builtin_amdgcn_exp2f(gl[1]);
            float ex2 = __builtin_amdgcn_exp2f(gl[2]);
            float ex3 = __builtin_amdgcn_exp2f(gl[3]);
            float s = (ex0 + ex1) + (ex2 + ex3);
            s += __shfl_xor(s, 16);
            rs = __builtin_amdgcn_rcpf(s);   // valid in quads 0-1; consumed by h0 lanes<16
            HI pa, pb;
            pa.h = pkrtz(ex0, ex1);
            pb.h = pkrtz(ex2, ex3);
            int va = __builtin_amdgcn_ds_bpermute(gsrc, pa.i);
            int vb = __builtin_amdgcn_ds_bpermute(gsrc, pb.i);
            HI gsel; gsel.i = (q & 1) ? vb : va;   // lane(q,t): ex[t,2q], ex[t,2q+1]
            float ga = (float)gsel.h[0];
            float gb = (float)gsel.h[1];

            // ---- this wave's 4 experts; Y rows live only in owned quads (others stay 0)
            float4_t Ya = b3F, Yb = zero4;
            #pragma unroll
            for (int e = 0; e < EPW_; ++e) {
                float4_t lo = MFMA_K16(W1F[e][0].h4, xB, zero4);
                float4_t hi = MFMA_K16(W1F[e][1].h4, xB, zero4);
                H8U u1;
                u1.h2[0] = relu2(pkrtz(lo[0], lo[1]));
                u1.h2[1] = relu2(pkrtz(lo[2], lo[3]));
                u1.h2[2] = relu2(pkrtz(hi[0], hi[1]));
                u1.h2[3] = relu2(pkrtz(hi[2], hi[3]));
                float4_t lo2 = MFMA_K32(W2F[e][0].h8, u1.h8, zero4);
                float4_t hi2 = MFMA_K32(W2F[e][1].h8, u1.h8, zero4);
                H8U u2;
                u2.h2[0] = relu2(pkrtz(lo2[0], lo2[1]) + B2R[e].h2[0]);
                u2.h2[1] = relu2(pkrtz(lo2[2], lo2[3]) + B2R[e].h2[1]);
                u2.h2[2] = relu2(pkrtz(hi2[0], hi2[1]) + B2R[e].h2[2]);
                u2.h2[3] = relu2(pkrtz(hi2[2], hi2[3]) + B2R[e].h2[3]);
                if (e & 1) Yb = MFMA_K32(W3F[e].h8, u2.h8, Yb);
                else       Ya = MFMA_K32(W3F[e].h8, u2.h8, Ya);
            }

            // ---- gated partial over this wave's 8 rows; quad-reduce (non-owned quads add 0)
            p0 = ga * (Ya[0] + Yb[0]) + gb * (Ya[2] + Yb[2]);
            p1 = ga * (Ya[1] + Yb[1]) + gb * (Ya[3] + Yb[3]);
            p0 += __shfl_xor(p0, 16);
            p0 += __shfl_xor(p0, 32);
            p1 += __shfl_xor(p1, 16);
            p1 += __shfl_xor(p1, 32);

            if (h == 1 && lane < 16) {
                float2_t w = {p0, p1};
                cb[it & 1][pr][t] = w;
            }
        }

        __syncthreads();   // one barrier per tile; parity buffer makes it sufficient

        if (active && h == 0 && lane < 16) {
            float2_t o = cb[it & 1][pr][t];
            float2_t w = {(p0 + o[0]) * rs, (p1 + o[1]) * rs};
            *(float2_t*)(out + ((size_t)tile * 16 + t) * 2) = w;
        }
    }
}

extern "C" void kernel_launch(void* const* d_in, const int* in_sizes, int n_in,
                              void* d_out, int out_size, void* d_ws, size_t ws_size,
                              hipStream_t stream) {
    const float* x   = (const float*)d_in[0];
    const float* W1  = (const float*)d_in[1];
    const float* b1  = (const float*)d_in[2];
    const float* W2  = (const float*)d_in[3];
    const float* b2  = (const float*)d_in[4];
    const float* W3  = (const float*)d_in[5];
    const float* b3  = (const float*)d_in[6];
    const float* Wg1 = (const float*)d_in[7];
    const float* bg1 = (const float*)d_in[8];
    const float* Wg2 = (const float*)d_in[9];
    const float* bg2 = (const float*)d_in[10];
    float* out = (float*)d_out;

    const int B      = in_sizes[0] / DIN_;
    const int nTiles = (B + 15) / 16;
    // 1024 blocks x 4 waves at <=128 VGPR (pinned waves_per_eu(4,4)) = 4 blocks/CU x 256 CU:
    // exact residency, no second scheduling round. 2048 pairs -> tpp = 32 at B=1M, zero tail.
    const int blocks = 1024;
    const int pairsTotal = blocks * 2;
    const int tpp = (nTiles + pairsTotal - 1) / pairsTotal;

    moe_kernel<<<blocks, 256, 0, stream>>>(x, W1, b1, W2, b2, W3, b3,
                                           Wg1, bg1, Wg2, bg2, out, nTiles, tpp);
}

// Round 4
// 179.274 us; speedup vs baseline: 1.0179x; 1.0179x over previous
//
#include <hip/hip_runtime.h>

// MoE: out[b,:] = sum_e softmax(gate(x))[b,e] * (W3_e^T @ relu(W2_e^T @ relu(W1_e^T @ x_b + b1) + b2) + b3)
// Tokens-as-N MFMA. L1 uses 16x16x16 f16 (K=7 useful, k=4q+j). L2/L3/gate-L2 use 16x16x32 f16
// with K-permutation pi(q*8+j)=q*4+(j&3)+16*(j>>2) so C/D layout == next layer's B layout
// in-lane (HW-verified across R2-R11: absmax 0.0156).
// R12: R9/R10 structure (1 wave owns a whole tile, all 8 experts, gate 1x, no LDS, no
//      barriers) + the CORRECT register budget. Allocator model solved by R9-R11 counters:
//      with MFMA in use, gfx950 splits the per-wave budget EVENLY arch/acc:
//        launch_bounds(.,2)/waves_per_eu(2,2) -> total 256 -> arch 128 (R9/R10: VGPR=128)
//        waves_per_eu(4,4)                    -> total 128 -> arch  64 (R11: VGPR=64)
//      Packed-f16 weight fragments must be arch VGPRs (VALU pkrtz can't write AGPRs), and
//      EPW=8 needs ~185 arch regs -> waves_per_eu(1,1): arch 256 + acc 256, zero spills.
//      1 wave/SIMD residency; latency hidden by intra-wave ILP (8 independent expert chains,
//      prefetched x). 512 blocks x 4 waves = 2048 waves; runs as two clean 32-tile rounds at
//      1 wave/SIMD (or one round if actual usage permits 2).

typedef _Float16 half2_t __attribute__((ext_vector_type(2)));
typedef _Float16 half4_t __attribute__((ext_vector_type(4)));
typedef _Float16 half8_t __attribute__((ext_vector_type(8)));
typedef __fp16   fp16v2  __attribute__((ext_vector_type(2)));
typedef float  float4_t __attribute__((ext_vector_type(4)));
typedef float  float2_t __attribute__((ext_vector_type(2)));
typedef int    int2_t   __attribute__((ext_vector_type(2)));
typedef int    int4_t   __attribute__((ext_vector_type(4)));

#define MFMA_K32(A, B, C) __builtin_amdgcn_mfma_f32_16x16x32_f16((A), (B), (C), 0, 0, 0)
#define MFMA_K16(A, B, C) __builtin_amdgcn_mfma_f32_16x16x16f16((A), (B), (C), 0, 0, 0)

static constexpr int E_ = 8, DIN_ = 6, H_ = 32, EPW_ = 8;   // experts per wave (all of them)

union H8U { half2_t h2[4]; half8_t h8; int4_t i4; };
union H4U { half2_t h2[2]; half4_t h4; int2_t i2; };
union HI  { half2_t h; int i; };
union PKU { fp16v2 p; half2_t h; };

__device__ __forceinline__ half2_t pkrtz(float a, float b) {
    PKU u; u.p = __builtin_amdgcn_cvt_pkrtz(a, b);
    return u.h;
}

__device__ __forceinline__ half2_t relu2(half2_t v) {
    const half2_t z = {(_Float16)0.0f, (_Float16)0.0f};
    return __builtin_elementwise_max(v, z);
}

__global__ __launch_bounds__(256)
__attribute__((amdgpu_waves_per_eu(1, 1)))
void moe_kernel(
    const float* __restrict__ x,  const float* __restrict__ W1, const float* __restrict__ b1,
    const float* __restrict__ W2, const float* __restrict__ b2, const float* __restrict__ W3,
    const float* __restrict__ b3, const float* __restrict__ Wg1, const float* __restrict__ bg1,
    const float* __restrict__ Wg2, const float* __restrict__ bg2,
    float* __restrict__ out, int nTiles, int tilesPerWave)
{
    const int tid  = threadIdx.x;
    const int lane = tid & 63;
    const int t    = lane & 15;   // token slot
    const int q    = lane >> 4;   // K-quad / row-quad
    const int gw   = (blockIdx.x << 2) + (tid >> 6);   // global wave id (waves independent)

    const float L2E = 1.44269504f;

    // ---- gate L1 A-fragments (K=16, k=4q+j; slots 0..5 = x features, 6 = bias-as-1.0)
    H4U G1[2];
    #pragma unroll
    for (int f = 0; f < 2; ++f) {
        float v0 = 0.f, v1 = 0.f, v2 = 0.f, v3 = 0.f;
        if (q == 0) {
            v0 = Wg1[0 * H_ + f * 16 + t]; v1 = Wg1[1 * H_ + f * 16 + t];
            v2 = Wg1[2 * H_ + f * 16 + t]; v3 = Wg1[3 * H_ + f * 16 + t];
        } else if (q == 1) {
            v0 = Wg1[4 * H_ + f * 16 + t]; v1 = Wg1[5 * H_ + f * 16 + t];
            v2 = bg1[f * 16 + t];          v3 = 0.f;
        }
        G1[f].h2[0] = pkrtz(v0, v1); G1[f].h2[1] = pkrtz(v2, v3);
    }
    // ---- gate L2 A-fragment (K=32, pi layout), pre-scaled by log2(e) so logits are exp2-ready
    H8U G2;
    #pragma unroll
    for (int p = 0; p < 4; ++p) {
        int c0 = ((p >> 1) << 4) + q * 4 + ((p & 1) << 1);
        float v0 = (t < E_) ? Wg2[c0 * E_ + t] * L2E : 0.f;
        float v1 = (t < E_) ? Wg2[(c0 + 1) * E_ + t] * L2E : 0.f;
        G2.h2[p] = pkrtz(v0, v1);
    }

    // ---- ALL 8 experts: L1 (K16), L2 (K32 pi), L3 (K32 pi, block-diag rows), b2 pairs
    H4U W1F[EPW_][2];
    H8U W2F[EPW_][2], W3F[EPW_], B2R[EPW_];
    #pragma unroll
    for (int e = 0; e < EPW_; ++e) {
        #pragma unroll
        for (int f = 0; f < 2; ++f) {
            float v0 = 0.f, v1 = 0.f, v2 = 0.f, v3 = 0.f;
            const float* We = W1 + (size_t)e * DIN_ * H_ + f * 16 + t;
            if (q == 0)      { v0 = We[0 * H_]; v1 = We[1 * H_]; v2 = We[2 * H_]; v3 = We[3 * H_]; }
            else if (q == 1) { v0 = We[4 * H_]; v1 = We[5 * H_]; v2 = b1[e * H_ + f * 16 + t]; }
            W1F[e][f].h2[0] = pkrtz(v0, v1); W1F[e][f].h2[1] = pkrtz(v2, v3);
        }
        #pragma unroll
        for (int p = 0; p < 4; ++p) {
            int c0 = ((p >> 1) << 4) + q * 4 + ((p & 1) << 1);
            W2F[e][0].h2[p] = pkrtz(W2[(e * H_ + c0) * H_ + 0  + t], W2[(e * H_ + c0 + 1) * H_ + 0  + t]);
            W2F[e][1].h2[p] = pkrtz(W2[(e * H_ + c0) * H_ + 16 + t], W2[(e * H_ + c0 + 1) * H_ + 16 + t]);
            B2R[e].h2[p]    = pkrtz(b2[e * H_ + c0], b2[e * H_ + c0 + 1]);
            float v0 = 0.f, v1 = 0.f;
            if ((t >> 1) == e) {      // Y rows m=(e,o): this expert's rows only
                v0 = W3[(e * H_ + c0) * 2 + (t & 1)];
                v1 = W3[(e * H_ + c0 + 1) * 2 + (t & 1)];
            }
            W3F[e].h2[p] = pkrtz(v0, v1);
        }
    }

    // ---- persistent C-inits: bg2 (log2-domain) for the gate; b3 for all 16 Y rows m=(e,o)
    float4_t bg2F, b3F;
    #pragma unroll
    for (int r = 0; r < 4; ++r) {
        int m = q * 4 + r;
        bg2F[r] = (m < E_) ? bg2[m] * L2E : 0.f;
        b3F[r]  = b3[m];
    }
    const float4_t zero4 = {0.f, 0.f, 0.f, 0.f};

    // gate pull: lane(q,t) fetches ex[t,2q],ex[t,2q+1] from lane (q>>1)*16+t
    const int gsrc = ((((q >> 1) << 4) | t) << 2);

    const int tile0 = gw * tilesPerWave;

    // ---- per-lane x source (loop-invariant): quad0 reads x[t][0..3]; quads>=1 read x[t][4..5]
    const int xo1 = (q == 0) ? 0 : 4;
    const int xo2 = (q == 0) ? 2 : 4;
    const float* xq = x + ((size_t)tile0 * 16 + t) * DIN_;
    float2_t la = {0.f, 0.f}, lb = {0.f, 0.f};
    if (tile0 < nTiles) {
        la = *(const float2_t*)(xq + xo1);
        lb = *(const float2_t*)(xq + xo2);
    }

    HI onei; onei.h = pkrtz(1.f, 0.f);
    const bool isq0 = (q == 0);

    for (int it = 0; it < tilesPerWave; ++it) {
        const int tile = tile0 + it;
        if (tile >= nTiles) break;          // uniform per wave

        // ---- x B-fragment (K=16): q0:(x0..x3) q1:(x4,x5,1,dc) q2/q3: dc (A=0 there)
        H4U ux;
        ux.h2[0] = pkrtz(la[0], la[1]);
        HI hb; hb.h = pkrtz(lb[0], lb[1]);
        HI se; se.i = isq0 ? hb.i : onei.i;
        ux.h2[1] = se.h;
        const half4_t xB = ux.h4;

        // ---- prefetch next tile's x
        if ((it + 1) < tilesPerWave && (tile + 1) < nTiles) {
            const float* xn = xq + (size_t)(it + 1) * 16 * DIN_;
            la = *(const float2_t*)(xn + xo1);
            lb = *(const float2_t*)(xn + xo2);
        }

        // ---- gate (computed ONCE per tile; logits already in log2 domain)
        float4_t hgLo = MFMA_K16(G1[0].h4, xB, zero4);
        float4_t hgHi = MFMA_K16(G1[1].h4, xB, zero4);
        H8U uh;
        uh.h2[0] = relu2(pkrtz(hgLo[0], hgLo[1]));
        uh.h2[1] = relu2(pkrtz(hgLo[2], hgLo[3]));
        uh.h2[2] = relu2(pkrtz(hgHi[0], hgHi[1]));
        uh.h2[3] = relu2(pkrtz(hgHi[2], hgHi[3]));
        float4_t gl = MFMA_K32(G2.h8, uh.h8, bg2F);

        // ---- softmax over 8 experts, no max-sub (|logit| bounded), normalization deferred
        float ex0 = __builtin_amdgcn_exp2f(gl[0]);
        float ex1 = __builtin_amdgcn_exp2f(gl[1]);
        float ex2 = __builtin_amdgcn_exp2f(gl[2]);
        float ex3 = __builtin_amdgcn_exp2f(gl[3]);
        float s = (ex0 + ex1) + (ex2 + ex3);
        s += __shfl_xor(s, 16);
        float rs = __builtin_amdgcn_rcpf(s);   // valid in quads 0-1; consumed by lanes<16 only
        HI pa, pb;
        pa.h = pkrtz(ex0, ex1);
        pb.h = pkrtz(ex2, ex3);
        int va = __builtin_amdgcn_ds_bpermute(gsrc, pa.i);
        int vb = __builtin_amdgcn_ds_bpermute(gsrc, pb.i);
        HI gsel; gsel.i = (q & 1) ? vb : va;       // lane(q,t): ex[t,2q], ex[t,2q+1]
        float ga = (float)gsel.h[0];
        float gb = (float)gsel.h[1];

        // ---- all 8 experts; Y rows m=(e,o) are disjoint across experts.
        //      Two accumulators halve the serial MFMA-accumulate chain.
        float4_t Ya = b3F, Yb = zero4;
        #pragma unroll
        for (int e = 0; e < EPW_; ++e) {
            float4_t lo = MFMA_K16(W1F[e][0].h4, xB, zero4);
            float4_t hi = MFMA_K16(W1F[e][1].h4, xB, zero4);
            H8U u1;
            u1.h2[0] = relu2(pkrtz(lo[0], lo[1]));
            u1.h2[1] = relu2(pkrtz(lo[2], lo[3]));
            u1.h2[2] = relu2(pkrtz(hi[0], hi[1]));
            u1.h2[3] = relu2(pkrtz(hi[2], hi[3]));
            float4_t lo2 = MFMA_K32(W2F[e][0].h8, u1.h8, zero4);
            float4_t hi2 = MFMA_K32(W2F[e][1].h8, u1.h8, zero4);
            H8U u2;
            u2.h2[0] = relu2(pkrtz(lo2[0], lo2[1]) + B2R[e].h2[0]);
            u2.h2[1] = relu2(pkrtz(lo2[2], lo2[3]) + B2R[e].h2[1]);
            u2.h2[2] = relu2(pkrtz(hi2[0], hi2[1]) + B2R[e].h2[2]);
            u2.h2[3] = relu2(pkrtz(hi2[2], hi2[3]) + B2R[e].h2[3]);
            if (e & 1) Yb = MFMA_K32(W3F[e].h8, u2.h8, Yb);
            else       Ya = MFMA_K32(W3F[e].h8, u2.h8, Ya);
        }

        // ---- gated partial: lane(q,t) holds Y rows m=4q+r -> experts {2q,2q+1}, o=r&1.
        //      ex-weighted (unnormalized), then sum over the 4 quads with shfl_xor. No LDS.
        float p0 = ga * (Ya[0] + Yb[0]) + gb * (Ya[2] + Yb[2]);
        float p1 = ga * (Ya[1] + Yb[1]) + gb * (Ya[3] + Yb[3]);
        p0 += __shfl_xor(p0, 16);
        p0 += __shfl_xor(p0, 32);
        p1 += __shfl_xor(p1, 16);
        p1 += __shfl_xor(p1, 32);

        if (lane < 16) {
            float2_t o = {p0 * rs, p1 * rs};
            *(float2_t*)(out + ((size_t)tile * 16 + t) * 2) = o;
        }
    }
}

extern "C" void kernel_launch(void* const* d_in, const int* in_sizes, int n_in,
                              void* d_out, int out_size, void* d_ws, size_t ws_size,
                              hipStream_t stream) {
    const float* x   = (const float*)d_in[0];
    const float* W1  = (const float*)d_in[1];
    const float* b1  = (const float*)d_in[2];
    const float* W2  = (const float*)d_in[3];
    const float* b2  = (const float*)d_in[4];
    const float* W3  = (const float*)d_in[5];
    const float* b3  = (const float*)d_in[6];
    const float* Wg1 = (const float*)d_in[7];
    const float* bg1 = (const float*)d_in[8];
    const float* Wg2 = (const float*)d_in[9];
    const float* bg2 = (const float*)d_in[10];
    float* out = (float*)d_out;

    const int B      = in_sizes[0] / DIN_;
    const int nTiles = (B + 15) / 16;
    // waves_per_eu(1,1): arch 256 + acc 256 per wave, zero spills at ~185 arch demand.
    // 512 blocks x 4 independent waves = 2048 waves; at 1 wave/SIMD this is two clean
    // 32-tile rounds over 1024 SIMDs (one round if actual usage permits 2 waves/SIMD).
    const int blocks = 512;
    const int wavesTotal = blocks * 4;
    const int tpw = (nTiles + wavesTotal - 1) / wavesTotal;

    moe_kernel<<<blocks, 256, 0, stream>>>(x, W1, b1, W2, b2, W3, b3,
                                           Wg1, bg1, Wg2, bg2, out, nTiles, tpw);
}

// Round 5
// 137.453 us; speedup vs baseline: 1.3276x; 1.3043x over previous
//
#include <hip/hip_runtime.h>

// MoE: out[b,:] = sum_e softmax(gate(x))[b,e] * (W3_e^T @ relu(W2_e^T @ relu(W1_e^T @ x_b + b1) + b2) + b3)
// Tokens-as-N MFMA. L1 uses 16x16x16 f16 (K=7 useful, k=4q+j). L2/L3/gate-L2 use 16x16x32 f16
// with K-permutation pi(q*8+j)=q*4+(j&3)+16*(j>>2) so C/D layout == next layer's B layout
// in-lane (HW-verified across R2-R12: absmax 0.0156).
// R13: EPW=8 single-wave-per-tile structure (R12: gate 1x, no loop barriers) made to FIT the
//      128-arch-VGPR budget of 2 waves/SIMD (even arch/acc split, proven R9-R12):
//      * W1+W2 fragment images -> LDS (24 KB/block, block-uniform, built once + 1 barrier).
//      * W3 fragments are per-lane SPARSE (lane's rows belong to expert t>>1 only): 32 regs
//        -> 4 regs (W3S) + per-expert cndmask at use.
//      * TWO tiles per iteration: weight ds_reads amortized over 2 tiles (12 KB/tile < VALU
//        cost) and 2 independent expert chains double intra-wave ILP (R12 @1 wave/SIMD sat
//        at VALU 38% from exposed dependency stalls).
//      waves_per_eu(2,2): arch 128 + acc 128; demand ~100 arch -> zero spills by construction.
//      512 blocks x 4 waves = 2048 waves = exact 2-wave/SIMD fill; 32 tiles/wave (16 pairs).

typedef _Float16 half2_t __attribute__((ext_vector_type(2)));
typedef _Float16 half4_t __attribute__((ext_vector_type(4)));
typedef _Float16 half8_t __attribute__((ext_vector_type(8)));
typedef __fp16   fp16v2  __attribute__((ext_vector_type(2)));
typedef float  float4_t __attribute__((ext_vector_type(4)));
typedef float  float2_t __attribute__((ext_vector_type(2)));
typedef int    int2_t   __attribute__((ext_vector_type(2)));
typedef int    int4_t   __attribute__((ext_vector_type(4)));

#define MFMA_K32(A, B, C) __builtin_amdgcn_mfma_f32_16x16x32_f16((A), (B), (C), 0, 0, 0)
#define MFMA_K16(A, B, C) __builtin_amdgcn_mfma_f32_16x16x16f16((A), (B), (C), 0, 0, 0)

static constexpr int E_ = 8, DIN_ = 6, H_ = 32;

union H8U { half2_t h2[4]; half8_t h8; int4_t i4; };
union H4U { half2_t h2[2]; half4_t h4; int2_t i2; };
union W1U { H4U f[2]; int4_t i4; };    // 16B: both L1 A-fragments of one expert
union HI  { half2_t h; int i; };
union PKU { fp16v2 p; half2_t h; };

__device__ __forceinline__ half2_t pkrtz(float a, float b) {
    PKU u; u.p = __builtin_amdgcn_cvt_pkrtz(a, b);
    return u.h;
}

__device__ __forceinline__ half2_t relu2(half2_t v) {
    const half2_t z = {(_Float16)0.0f, (_Float16)0.0f};
    return __builtin_elementwise_max(v, z);
}

// full gate chain for one tile: logits (log2 domain) -> ex weights for this lane's expert
// pair {2q,2q+1} + deferred-normalization reciprocal (valid in quads 0-1)
__device__ __forceinline__ void gate_eval(
    half4_t xB, const H4U* G1, const H8U& G2, float4_t bg2F, float4_t zero4,
    int gsrc, int q, float& ga, float& gb, float& rs)
{
    float4_t hgLo = MFMA_K16(G1[0].h4, xB, zero4);
    float4_t hgHi = MFMA_K16(G1[1].h4, xB, zero4);
    H8U uh;
    uh.h2[0] = relu2(pkrtz(hgLo[0], hgLo[1]));
    uh.h2[1] = relu2(pkrtz(hgLo[2], hgLo[3]));
    uh.h2[2] = relu2(pkrtz(hgHi[0], hgHi[1]));
    uh.h2[3] = relu2(pkrtz(hgHi[2], hgHi[3]));
    float4_t gl = MFMA_K32(G2.h8, uh.h8, bg2F);
    float ex0 = __builtin_amdgcn_exp2f(gl[0]);
    float ex1 = __builtin_amdgcn_exp2f(gl[1]);
    float ex2 = __builtin_amdgcn_exp2f(gl[2]);
    float ex3 = __builtin_amdgcn_exp2f(gl[3]);
    float s = (ex0 + ex1) + (ex2 + ex3);
    s += __shfl_xor(s, 16);
    rs = __builtin_amdgcn_rcpf(s);
    HI pa, pb;
    pa.h = pkrtz(ex0, ex1);
    pb.h = pkrtz(ex2, ex3);
    int va = __builtin_amdgcn_ds_bpermute(gsrc, pa.i);
    int vb = __builtin_amdgcn_ds_bpermute(gsrc, pb.i);
    HI gsel; gsel.i = (q & 1) ? vb : va;   // lane(q,t): ex[t,2q], ex[t,2q+1]
    ga = (float)gsel.h[0];
    gb = (float)gsel.h[1];
}

__global__ __launch_bounds__(256)
__attribute__((amdgpu_waves_per_eu(2, 2)))
void moe_kernel(
    const float* __restrict__ x,  const float* __restrict__ W1, const float* __restrict__ b1,
    const float* __restrict__ W2, const float* __restrict__ b2, const float* __restrict__ W3,
    const float* __restrict__ b3, const float* __restrict__ Wg1, const float* __restrict__ bg1,
    const float* __restrict__ Wg2, const float* __restrict__ bg2,
    float* __restrict__ out, int nTiles, int tilesPerWave)
{
    const int tid  = threadIdx.x;
    const int lane = tid & 63;
    const int t    = lane & 15;   // token slot
    const int q    = lane >> 4;   // K-quad / row-quad
    const int wv   = tid >> 6;    // wave in block
    const int gw   = (blockIdx.x << 2) + wv;   // global wave id (waves independent in loop)
    const int eo   = t >> 1;      // the ONE expert whose L3 rows this lane holds

    // block-uniform weight images (every wave reads the same fragments)
    __shared__ W1U w1img[E_][64];        //  8 KB: [e][lane] -> both L1 A-fragments
    __shared__ H8U w2img[E_][2][64];     // 16 KB: [e][half][lane] -> L2 A-fragment

    const float L2E = 1.44269504f;

    // ---- build LDS weight images: wave wv packs experts {2wv, 2wv+1} (pi layout as R2-R12)
    #pragma unroll
    for (int j = 0; j < 2; ++j) {
        const int e = wv * 2 + j;
        W1U w1v;
        #pragma unroll
        for (int f = 0; f < 2; ++f) {
            float v0 = 0.f, v1 = 0.f, v2 = 0.f, v3 = 0.f;
            const float* We = W1 + (size_t)e * DIN_ * H_ + f * 16 + t;
            if (q == 0)      { v0 = We[0 * H_]; v1 = We[1 * H_]; v2 = We[2 * H_]; v3 = We[3 * H_]; }
            else if (q == 1) { v0 = We[4 * H_]; v1 = We[5 * H_]; v2 = b1[e * H_ + f * 16 + t]; }
            w1v.f[f].h2[0] = pkrtz(v0, v1); w1v.f[f].h2[1] = pkrtz(v2, v3);
        }
        w1img[e][lane] = w1v;
        H8U w2lo, w2hi;
        #pragma unroll
        for (int p = 0; p < 4; ++p) {
            int c0 = ((p >> 1) << 4) + q * 4 + ((p & 1) << 1);
            w2lo.h2[p] = pkrtz(W2[(e * H_ + c0) * H_ + 0  + t], W2[(e * H_ + c0 + 1) * H_ + 0  + t]);
            w2hi.h2[p] = pkrtz(W2[(e * H_ + c0) * H_ + 16 + t], W2[(e * H_ + c0 + 1) * H_ + 16 + t]);
        }
        w2img[e][0][lane] = w2lo;
        w2img[e][1][lane] = w2hi;
    }

    // ---- gate L1 A-fragments (K=16, k=4q+j; slots 0..5 = x features, 6 = bias-as-1.0)
    H4U G1[2];
    #pragma unroll
    for (int f = 0; f < 2; ++f) {
        float v0 = 0.f, v1 = 0.f, v2 = 0.f, v3 = 0.f;
        if (q == 0) {
            v0 = Wg1[0 * H_ + f * 16 + t]; v1 = Wg1[1 * H_ + f * 16 + t];
            v2 = Wg1[2 * H_ + f * 16 + t]; v3 = Wg1[3 * H_ + f * 16 + t];
        } else if (q == 1) {
            v0 = Wg1[4 * H_ + f * 16 + t]; v1 = Wg1[5 * H_ + f * 16 + t];
            v2 = bg1[f * 16 + t];          v3 = 0.f;
        }
        G1[f].h2[0] = pkrtz(v0, v1); G1[f].h2[1] = pkrtz(v2, v3);
    }
    // ---- gate L2 A-fragment (K=32, pi layout), pre-scaled by log2(e)
    H8U G2;
    #pragma unroll
    for (int p = 0; p < 4; ++p) {
        int c0 = ((p >> 1) << 4) + q * 4 + ((p & 1) << 1);
        float v0 = (t < E_) ? Wg2[c0 * E_ + t] * L2E : 0.f;
        float v1 = (t < E_) ? Wg2[(c0 + 1) * E_ + t] * L2E : 0.f;
        G2.h2[p] = pkrtz(v0, v1);
    }

    // ---- W3 sparse fragment: this lane's rows m=(eo,o) only (4 regs; masked per expert at use)
    H8U W3S;
    #pragma unroll
    for (int p = 0; p < 4; ++p) {
        int c0 = ((p >> 1) << 4) + q * 4 + ((p & 1) << 1);
        W3S.h2[p] = pkrtz(W3[(eo * H_ + c0) * 2 + (t & 1)], W3[(eo * H_ + c0 + 1) * 2 + (t & 1)]);
    }

    // ---- b2 packed-add fragments (32 regs; proven form)
    H8U B2R[E_];
    #pragma unroll
    for (int e = 0; e < E_; ++e) {
        #pragma unroll
        for (int p = 0; p < 4; ++p) {
            int c0 = ((p >> 1) << 4) + q * 4 + ((p & 1) << 1);
            B2R[e].h2[p] = pkrtz(b2[e * H_ + c0], b2[e * H_ + c0 + 1]);
        }
    }

    // ---- persistent C-inits: bg2 (log2 domain), b3 for all 16 Y rows m=(e,o)
    float4_t bg2F, b3F;
    #pragma unroll
    for (int r = 0; r < 4; ++r) {
        int m = q * 4 + r;
        bg2F[r] = (m < E_) ? bg2[m] * L2E : 0.f;
        b3F[r]  = b3[m];
    }
    const float4_t zero4 = {0.f, 0.f, 0.f, 0.f};
    const int4_t  zeroi  = {0, 0, 0, 0};

    // gate pull: lane(q,t) fetches ex[t,2q],ex[t,2q+1] from lane (q>>1)*16+t
    const int gsrc = ((((q >> 1) << 4) | t) << 2);

    __syncthreads();   // LDS images ready; NO barriers inside the loop

    const int tile0 = gw * tilesPerWave;

    // ---- per-lane x source: quad0 reads x[t][0..3]; quads>=1 read x[t][4..5]
    const int xo1 = (q == 0) ? 0 : 4;
    const int xo2 = (q == 0) ? 2 : 4;
    const float* xq = x + ((size_t)tile0 * 16 + t) * DIN_;
    float2_t la0 = {0.f, 0.f}, lb0 = {0.f, 0.f}, la1 = {0.f, 0.f}, lb1 = {0.f, 0.f};
    if (tile0 < nTiles)     { la0 = *(const float2_t*)(xq + xo1); lb0 = *(const float2_t*)(xq + xo2); }
    if (tile0 + 1 < nTiles) { la1 = *(const float2_t*)(xq + 16 * DIN_ + xo1);
                              lb1 = *(const float2_t*)(xq + 16 * DIN_ + xo2); }

    HI onei; onei.h = pkrtz(1.f, 0.f);
    const bool isq0 = (q == 0);

    // ---- main loop: TWO tiles per iteration (weights read once per pair; 2x ILP)
    for (int it = 0; it < tilesPerWave; it += 2) {
        const int tA = tile0 + it;
        const int tB = tA + 1;
        if (tA >= nTiles) break;            // uniform per wave
        const bool actB = (tB < nTiles);

        // x B-fragments (K=16): q0:(x0..x3) q1:(x4,x5,1,dc) q2/q3: dc (A=0 there)
        H4U uxA, uxB;
        uxA.h2[0] = pkrtz(la0[0], la0[1]);
        { HI hb; hb.h = pkrtz(lb0[0], lb0[1]); HI se; se.i = isq0 ? hb.i : onei.i; uxA.h2[1] = se.h; }
        uxB.h2[0] = pkrtz(la1[0], la1[1]);
        { HI hb; hb.h = pkrtz(lb1[0], lb1[1]); HI se; se.i = isq0 ? hb.i : onei.i; uxB.h2[1] = se.h; }
        const half4_t xBA = uxA.h4;
        const half4_t xBB = uxB.h4;

        // prefetch next pair's x
        if (it + 2 < tilesPerWave) {
            const float* xn = xq + (size_t)(it + 2) * 16 * DIN_;
            if (tA + 2 < nTiles) { la0 = *(const float2_t*)(xn + xo1); lb0 = *(const float2_t*)(xn + xo2); }
            if (tB + 2 < nTiles) { la1 = *(const float2_t*)(xn + 16 * DIN_ + xo1);
                                   lb1 = *(const float2_t*)(xn + 16 * DIN_ + xo2); }
        }

        // gates (once per tile; independent chains interleave with expert MFMAs)
        float gaA, gbA, rsA, gaB, gbB, rsB;
        gate_eval(xBA, G1, G2, bg2F, zero4, gsrc, q, gaA, gbA, rsA);
        gate_eval(xBB, G1, G2, bg2F, zero4, gsrc, q, gaB, gbB, rsB);

        // all 8 experts x 2 tiles; weights from LDS once per expert
        float4_t YaA = b3F, YbA = zero4, YaB = b3F, YbB = zero4;
        #pragma unroll
        for (int e = 0; e < E_; ++e) {
            W1U w1v  = w1img[e][lane];
            H8U w2lo = w2img[e][0][lane];
            H8U w2hi = w2img[e][1][lane];
            H8U a3;  a3.i4 = (eo == e) ? W3S.i4 : zeroi;   // sparse L3 rows: mask per expert

            // --- tile A chain
            float4_t loA = MFMA_K16(w1v.f[0].h4, xBA, zero4);
            float4_t hiA = MFMA_K16(w1v.f[1].h4, xBA, zero4);
            H8U u1A;
            u1A.h2[0] = relu2(pkrtz(loA[0], loA[1]));
            u1A.h2[1] = relu2(pkrtz(loA[2], loA[3]));
            u1A.h2[2] = relu2(pkrtz(hiA[0], hiA[1]));
            u1A.h2[3] = relu2(pkrtz(hiA[2], hiA[3]));
            float4_t lo2A = MFMA_K32(w2lo.h8, u1A.h8, zero4);
            float4_t hi2A = MFMA_K32(w2hi.h8, u1A.h8, zero4);
            H8U u2A;
            u2A.h2[0] = relu2(pkrtz(lo2A[0], lo2A[1]) + B2R[e].h2[0]);
            u2A.h2[1] = relu2(pkrtz(lo2A[2], lo2A[3]) + B2R[e].h2[1]);
            u2A.h2[2] = relu2(pkrtz(hi2A[0], hi2A[1]) + B2R[e].h2[2]);
            u2A.h2[3] = relu2(pkrtz(hi2A[2], hi2A[3]) + B2R[e].h2[3]);
            if (e & 1) YbA = MFMA_K32(a3.h8, u2A.h8, YbA);
            else       YaA = MFMA_K32(a3.h8, u2A.h8, YaA);

            // --- tile B chain (independent)
            float4_t loB = MFMA_K16(w1v.f[0].h4, xBB, zero4);
            float4_t hiB = MFMA_K16(w1v.f[1].h4, xBB, zero4);
            H8U u1B;
            u1B.h2[0] = relu2(pkrtz(loB[0], loB[1]));
            u1B.h2[1] = relu2(pkrtz(loB[2], loB[3]));
            u1B.h2[2] = relu2(pkrtz(hiB[0], hiB[1]));
            u1B.h2[3] = relu2(pkrtz(hiB[2], hiB[3]));
            float4_t lo2B = MFMA_K32(w2lo.h8, u1B.h8, zero4);
            float4_t hi2B = MFMA_K32(w2hi.h8, u1B.h8, zero4);
            H8U u2B;
            u2B.h2[0] = relu2(pkrtz(lo2B[0], lo2B[1]) + B2R[e].h2[0]);
            u2B.h2[1] = relu2(pkrtz(lo2B[2], lo2B[3]) + B2R[e].h2[1]);
            u2B.h2[2] = relu2(pkrtz(hi2B[0], hi2B[1]) + B2R[e].h2[2]);
            u2B.h2[3] = relu2(pkrtz(hi2B[2], hi2B[3]) + B2R[e].h2[3]);
            if (e & 1) YbB = MFMA_K32(a3.h8, u2B.h8, YbB);
            else       YaB = MFMA_K32(a3.h8, u2B.h8, YaB);
        }

        // epilogue tile A: lane(q,t) holds Y rows m=4q+r -> experts {2q,2q+1}, o=r&1
        {
            float p0 = gaA * (YaA[0] + YbA[0]) + gbA * (YaA[2] + YbA[2]);
            float p1 = gaA * (YaA[1] + YbA[1]) + gbA * (YaA[3] + YbA[3]);
            p0 += __shfl_xor(p0, 16);
            p0 += __shfl_xor(p0, 32);
            p1 += __shfl_xor(p1, 16);
            p1 += __shfl_xor(p1, 32);
            if (lane < 16) {
                float2_t o = {p0 * rsA, p1 * rsA};
                *(float2_t*)(out + ((size_t)tA * 16 + t) * 2) = o;
            }
        }
        // epilogue tile B
        if (actB) {
            float p0 = gaB * (YaB[0] + YbB[0]) + gbB * (YaB[2] + YbB[2]);
            float p1 = gaB * (YaB[1] + YbB[1]) + gbB * (YaB[3] + YbB[3]);
            p0 += __shfl_xor(p0, 16);
            p0 += __shfl_xor(p0, 32);
            p1 += __shfl_xor(p1, 16);
            p1 += __shfl_xor(p1, 32);
            if (lane < 16) {
                float2_t o = {p0 * rsB, p1 * rsB};
                *(float2_t*)(out + ((size_t)tB * 16 + t) * 2) = o;
            }
        }
    }
}

extern "C" void kernel_launch(void* const* d_in, const int* in_sizes, int n_in,
                              void* d_out, int out_size, void* d_ws, size_t ws_size,
                              hipStream_t stream) {
    const float* x   = (const float*)d_in[0];
    const float* W1  = (const float*)d_in[1];
    const float* b1  = (const float*)d_in[2];
    const float* W2  = (const float*)d_in[3];
    const float* b2  = (const float*)d_in[4];
    const float* W3  = (const float*)d_in[5];
    const float* b3  = (const float*)d_in[6];
    const float* Wg1 = (const float*)d_in[7];
    const float* bg1 = (const float*)d_in[8];
    const float* Wg2 = (const float*)d_in[9];
    const float* bg2 = (const float*)d_in[10];
    float* out = (float*)d_out;

    const int B      = in_sizes[0] / DIN_;
    const int nTiles = (B + 15) / 16;
    // waves_per_eu(2,2): arch 128 + acc 128 per wave; arch demand ~100 -> zero spills.
    // 512 blocks x 4 waves = 2048 waves = exact 2-wave/SIMD fill (2 blocks/CU, 48 KB LDS/CU).
    // nTiles (65536) / 2048 = 32 tiles/wave = 16 pairs, zero tail.
    const int blocks = 512;
    const int wavesTotal = blocks * 4;
    const int tpw = (nTiles + wavesTotal - 1) / wavesTotal;

    moe_kernel<<<blocks, 256, 0, stream>>>(x, W1, b1, W2, b2, W3, b3,
                                           Wg1, bg1, Wg2, bg2, out, nTiles, tpw);
}

// Round 6
// 134.509 us; speedup vs baseline: 1.3567x; 1.0219x over previous
//
#include <hip/hip_runtime.h>

// MoE: out[b,:] = sum_e softmax(gate(x))[b,e] * (W3_e^T @ relu(W2_e^T @ relu(W1_e^T @ x_b + b1) + b2) + b3)
// Tokens-as-N MFMA. L1 uses 16x16x16 f16 (K=7 useful, k=4q+j). L2/L3/gate-L2 use 16x16x32 f16
// with K-permutation pi(q*8+j)=q*4+(j&3)+16*(j>>2) so C/D layout == next layer's B layout
// in-lane (HW-verified across R2-R13: absmax 0.0156).
// R14: R13 (LDS weight images, sparse W3, 2 waves/SIMD at the proven 128-arch-VGPR even-split
//      cap, zero spills) widened from 2 -> 4 tiles per iteration. R13 measured ~2325 cyc/tile
//      against ~1000 cyc of real issue: half the wall clock is dependency-stall exposure at
//      2 waves/SIMD. 4 independent per-tile chains per weight read double the ready-instr
//      pool at every stall point and halve weight ds_reads/tile again (12 -> 8 b128).
//      B2R (32 regs) joins the LDS images to keep arch demand ~100 <= 128: zero spills by
//      construction (falsifiable via WRITE_SIZE). LDS 32 KB/block, 64 KB/CU at 2 blocks/CU.
//      512 blocks x 4 waves = 2048 waves = exact 2-wave/SIMD fill; 32 tiles/wave = 8 iters.

typedef _Float16 half2_t __attribute__((ext_vector_type(2)));
typedef _Float16 half4_t __attribute__((ext_vector_type(4)));
typedef _Float16 half8_t __attribute__((ext_vector_type(8)));
typedef __fp16   fp16v2  __attribute__((ext_vector_type(2)));
typedef float  float4_t __attribute__((ext_vector_type(4)));
typedef float  float2_t __attribute__((ext_vector_type(2)));
typedef int    int2_t   __attribute__((ext_vector_type(2)));
typedef int    int4_t   __attribute__((ext_vector_type(4)));

#define MFMA_K32(A, B, C) __builtin_amdgcn_mfma_f32_16x16x32_f16((A), (B), (C), 0, 0, 0)
#define MFMA_K16(A, B, C) __builtin_amdgcn_mfma_f32_16x16x16f16((A), (B), (C), 0, 0, 0)

static constexpr int E_ = 8, DIN_ = 6, H_ = 32, TB_ = 4;   // tiles per iteration

union H8U { half2_t h2[4]; half8_t h8; int4_t i4; };
union H4U { half2_t h2[2]; half4_t h4; int2_t i2; };
union W1U { H4U f[2]; int4_t i4; };    // 16B: both L1 A-fragments of one expert
union HI  { half2_t h; int i; };
union PKU { fp16v2 p; half2_t h; };

__device__ __forceinline__ half2_t pkrtz(float a, float b) {
    PKU u; u.p = __builtin_amdgcn_cvt_pkrtz(a, b);
    return u.h;
}

__device__ __forceinline__ half2_t relu2(half2_t v) {
    const half2_t z = {(_Float16)0.0f, (_Float16)0.0f};
    return __builtin_elementwise_max(v, z);
}

// full gate chain for one tile: logits (log2 domain) -> ex weights for this lane's expert
// pair {2q,2q+1} + deferred-normalization reciprocal (valid in quads 0-1)
__device__ __forceinline__ void gate_eval(
    half4_t xB, const H4U* G1, const H8U& G2, float4_t bg2F, float4_t zero4,
    int gsrc, int q, float& ga, float& gb, float& rs)
{
    float4_t hgLo = MFMA_K16(G1[0].h4, xB, zero4);
    float4_t hgHi = MFMA_K16(G1[1].h4, xB, zero4);
    H8U uh;
    uh.h2[0] = relu2(pkrtz(hgLo[0], hgLo[1]));
    uh.h2[1] = relu2(pkrtz(hgLo[2], hgLo[3]));
    uh.h2[2] = relu2(pkrtz(hgHi[0], hgHi[1]));
    uh.h2[3] = relu2(pkrtz(hgHi[2], hgHi[3]));
    float4_t gl = MFMA_K32(G2.h8, uh.h8, bg2F);
    float ex0 = __builtin_amdgcn_exp2f(gl[0]);
    float ex1 = __builtin_amdgcn_exp2f(gl[1]);
    float ex2 = __builtin_amdgcn_exp2f(gl[2]);
    float ex3 = __builtin_amdgcn_exp2f(gl[3]);
    float s = (ex0 + ex1) + (ex2 + ex3);
    s += __shfl_xor(s, 16);
    rs = __builtin_amdgcn_rcpf(s);
    HI pa, pb;
    pa.h = pkrtz(ex0, ex1);
    pb.h = pkrtz(ex2, ex3);
    int va = __builtin_amdgcn_ds_bpermute(gsrc, pa.i);
    int vb = __builtin_amdgcn_ds_bpermute(gsrc, pb.i);
    HI gsel; gsel.i = (q & 1) ? vb : va;   // lane(q,t): ex[t,2q], ex[t,2q+1]
    ga = (float)gsel.h[0];
    gb = (float)gsel.h[1];
}

__global__ __launch_bounds__(256)
__attribute__((amdgpu_waves_per_eu(2, 2)))
void moe_kernel(
    const float* __restrict__ x,  const float* __restrict__ W1, const float* __restrict__ b1,
    const float* __restrict__ W2, const float* __restrict__ b2, const float* __restrict__ W3,
    const float* __restrict__ b3, const float* __restrict__ Wg1, const float* __restrict__ bg1,
    const float* __restrict__ Wg2, const float* __restrict__ bg2,
    float* __restrict__ out, int nTiles, int tilesPerWave)
{
    const int tid  = threadIdx.x;
    const int lane = tid & 63;
    const int t    = lane & 15;   // token slot
    const int q    = lane >> 4;   // K-quad / row-quad
    const int wv   = tid >> 6;    // wave in block
    const int gw   = (blockIdx.x << 2) + wv;   // global wave id (waves independent in loop)
    const int eo   = t >> 1;      // the ONE expert whose L3 rows this lane holds

    // block-uniform weight images (every wave reads the same fragments)
    __shared__ W1U w1img[E_][64];        //  8 KB: [e][lane] -> both L1 A-fragments
    __shared__ H8U w2img[E_][2][64];     // 16 KB: [e][half][lane] -> L2 A-fragment
    __shared__ H8U b2img[E_][64];        //  8 KB: [e][lane] -> b2 packed-add fragment

    const float L2E = 1.44269504f;

    // ---- build LDS weight images: wave wv packs experts {2wv, 2wv+1} (pi layout as R2-R13)
    #pragma unroll
    for (int j = 0; j < 2; ++j) {
        const int e = wv * 2 + j;
        W1U w1v;
        #pragma unroll
        for (int f = 0; f < 2; ++f) {
            float v0 = 0.f, v1 = 0.f, v2 = 0.f, v3 = 0.f;
            const float* We = W1 + (size_t)e * DIN_ * H_ + f * 16 + t;
            if (q == 0)      { v0 = We[0 * H_]; v1 = We[1 * H_]; v2 = We[2 * H_]; v3 = We[3 * H_]; }
            else if (q == 1) { v0 = We[4 * H_]; v1 = We[5 * H_]; v2 = b1[e * H_ + f * 16 + t]; }
            w1v.f[f].h2[0] = pkrtz(v0, v1); w1v.f[f].h2[1] = pkrtz(v2, v3);
        }
        w1img[e][lane] = w1v;
        H8U w2lo, w2hi, b2v;
        #pragma unroll
        for (int p = 0; p < 4; ++p) {
            int c0 = ((p >> 1) << 4) + q * 4 + ((p & 1) << 1);
            w2lo.h2[p] = pkrtz(W2[(e * H_ + c0) * H_ + 0  + t], W2[(e * H_ + c0 + 1) * H_ + 0  + t]);
            w2hi.h2[p] = pkrtz(W2[(e * H_ + c0) * H_ + 16 + t], W2[(e * H_ + c0 + 1) * H_ + 16 + t]);
            b2v.h2[p]  = pkrtz(b2[e * H_ + c0], b2[e * H_ + c0 + 1]);
        }
        w2img[e][0][lane] = w2lo;
        w2img[e][1][lane] = w2hi;
        b2img[e][lane]    = b2v;
    }

    // ---- gate L1 A-fragments (K=16, k=4q+j; slots 0..5 = x features, 6 = bias-as-1.0)
    H4U G1[2];
    #pragma unroll
    for (int f = 0; f < 2; ++f) {
        float v0 = 0.f, v1 = 0.f, v2 = 0.f, v3 = 0.f;
        if (q == 0) {
            v0 = Wg1[0 * H_ + f * 16 + t]; v1 = Wg1[1 * H_ + f * 16 + t];
            v2 = Wg1[2 * H_ + f * 16 + t]; v3 = Wg1[3 * H_ + f * 16 + t];
        } else if (q == 1) {
            v0 = Wg1[4 * H_ + f * 16 + t]; v1 = Wg1[5 * H_ + f * 16 + t];
            v2 = bg1[f * 16 + t];          v3 = 0.f;
        }
        G1[f].h2[0] = pkrtz(v0, v1); G1[f].h2[1] = pkrtz(v2, v3);
    }
    // ---- gate L2 A-fragment (K=32, pi layout), pre-scaled by log2(e)
    H8U G2;
    #pragma unroll
    for (int p = 0; p < 4; ++p) {
        int c0 = ((p >> 1) << 4) + q * 4 + ((p & 1) << 1);
        float v0 = (t < E_) ? Wg2[c0 * E_ + t] * L2E : 0.f;
        float v1 = (t < E_) ? Wg2[(c0 + 1) * E_ + t] * L2E : 0.f;
        G2.h2[p] = pkrtz(v0, v1);
    }

    // ---- W3 sparse fragment: this lane's rows m=(eo,o) only (4 regs; masked per expert at use)
    H8U W3S;
    #pragma unroll
    for (int p = 0; p < 4; ++p) {
        int c0 = ((p >> 1) << 4) + q * 4 + ((p & 1) << 1);
        W3S.h2[p] = pkrtz(W3[(eo * H_ + c0) * 2 + (t & 1)], W3[(eo * H_ + c0 + 1) * 2 + (t & 1)]);
    }

    // ---- persistent C-inits: bg2 (log2 domain), b3 for all 16 Y rows m=(e,o)
    float4_t bg2F, b3F;
    #pragma unroll
    for (int r = 0; r < 4; ++r) {
        int m = q * 4 + r;
        bg2F[r] = (m < E_) ? bg2[m] * L2E : 0.f;
        b3F[r]  = b3[m];
    }
    const float4_t zero4 = {0.f, 0.f, 0.f, 0.f};
    const int4_t  zeroi  = {0, 0, 0, 0};

    // gate pull: lane(q,t) fetches ex[t,2q],ex[t,2q+1] from lane (q>>1)*16+t
    const int gsrc = ((((q >> 1) << 4) | t) << 2);

    __syncthreads();   // LDS images ready; NO barriers inside the loop

    const int tile0 = gw * tilesPerWave;

    // ---- per-lane x source: quad0 reads x[t][0..3]; quads>=1 read x[t][4..5]
    const int xo1 = (q == 0) ? 0 : 4;
    const int xo2 = (q == 0) ? 2 : 4;
    const float* xq = x + ((size_t)tile0 * 16 + t) * DIN_;
    float2_t la[TB_], lb[TB_];
    #pragma unroll
    for (int u = 0; u < TB_; ++u) {
        la[u] = float2_t{0.f, 0.f};
        lb[u] = float2_t{0.f, 0.f};
        if (tile0 + u < nTiles) {
            la[u] = *(const float2_t*)(xq + (size_t)u * 16 * DIN_ + xo1);
            lb[u] = *(const float2_t*)(xq + (size_t)u * 16 * DIN_ + xo2);
        }
    }

    HI onei; onei.h = pkrtz(1.f, 0.f);
    const bool isq0 = (q == 0);

    // ---- main loop: FOUR tiles per iteration (weights read once per quad; 4x ILP)
    for (int it = 0; it < tilesPerWave; it += TB_) {
        const int tb = tile0 + it;
        if (tb >= nTiles) break;            // uniform per wave

        // x B-fragments (K=16): q0:(x0..x3) q1:(x4,x5,1,dc) q2/q3: dc (A=0 there)
        H4U ux[TB_];
        #pragma unroll
        for (int u = 0; u < TB_; ++u) {
            ux[u].h2[0] = pkrtz(la[u][0], la[u][1]);
            HI hb; hb.h = pkrtz(lb[u][0], lb[u][1]);
            HI se; se.i = isq0 ? hb.i : onei.i;
            ux[u].h2[1] = se.h;
        }

        // prefetch next quad's x
        if (it + TB_ < tilesPerWave) {
            const float* xn = xq + (size_t)(it + TB_) * 16 * DIN_;
            #pragma unroll
            for (int u = 0; u < TB_; ++u) {
                if (tb + TB_ + u < nTiles) {
                    la[u] = *(const float2_t*)(xn + (size_t)u * 16 * DIN_ + xo1);
                    lb[u] = *(const float2_t*)(xn + (size_t)u * 16 * DIN_ + xo2);
                }
            }
        }

        // gates (once per tile; 4 independent chains interleave with each other)
        float ga[TB_], gb[TB_], rs[TB_];
        #pragma unroll
        for (int u = 0; u < TB_; ++u)
            gate_eval(ux[u].h4, G1, G2, bg2F, zero4, gsrc, q, ga[u], gb[u], rs[u]);

        // all 8 experts x 4 tiles; weights read from LDS once per expert
        float4_t Ya[TB_], Yb[TB_];
        #pragma unroll
        for (int u = 0; u < TB_; ++u) { Ya[u] = b3F; Yb[u] = zero4; }
        #pragma unroll
        for (int e = 0; e < E_; ++e) {
            W1U w1v  = w1img[e][lane];
            H8U w2lo = w2img[e][0][lane];
            H8U w2hi = w2img[e][1][lane];
            H8U b2v  = b2img[e][lane];
            H8U a3;  a3.i4 = (eo == e) ? W3S.i4 : zeroi;   // sparse L3 rows: mask per expert

            #pragma unroll
            for (int u = 0; u < TB_; ++u) {
                float4_t lo = MFMA_K16(w1v.f[0].h4, ux[u].h4, zero4);
                float4_t hi = MFMA_K16(w1v.f[1].h4, ux[u].h4, zero4);
                H8U u1;
                u1.h2[0] = relu2(pkrtz(lo[0], lo[1]));
                u1.h2[1] = relu2(pkrtz(lo[2], lo[3]));
                u1.h2[2] = relu2(pkrtz(hi[0], hi[1]));
                u1.h2[3] = relu2(pkrtz(hi[2], hi[3]));
                float4_t lo2 = MFMA_K32(w2lo.h8, u1.h8, zero4);
                float4_t hi2 = MFMA_K32(w2hi.h8, u1.h8, zero4);
                H8U u2;
                u2.h2[0] = relu2(pkrtz(lo2[0], lo2[1]) + b2v.h2[0]);
                u2.h2[1] = relu2(pkrtz(lo2[2], lo2[3]) + b2v.h2[1]);
                u2.h2[2] = relu2(pkrtz(hi2[0], hi2[1]) + b2v.h2[2]);
                u2.h2[3] = relu2(pkrtz(hi2[2], hi2[3]) + b2v.h2[3]);
                if (e & 1) Yb[u] = MFMA_K32(a3.h8, u2.h8, Yb[u]);
                else       Ya[u] = MFMA_K32(a3.h8, u2.h8, Ya[u]);
            }
        }

        // epilogues: lane(q,t) holds Y rows m=4q+r -> experts {2q,2q+1}, o=r&1
        #pragma unroll
        for (int u = 0; u < TB_; ++u) {
            const int tile = tb + u;
            float p0 = ga[u] * (Ya[u][0] + Yb[u][0]) + gb[u] * (Ya[u][2] + Yb[u][2]);
            float p1 = ga[u] * (Ya[u][1] + Yb[u][1]) + gb[u] * (Ya[u][3] + Yb[u][3]);
            p0 += __shfl_xor(p0, 16);
            p0 += __shfl_xor(p0, 32);
            p1 += __shfl_xor(p1, 16);
            p1 += __shfl_xor(p1, 32);
            if (tile < nTiles && lane < 16) {
                float2_t o = {p0 * rs[u], p1 * rs[u]};
                *(float2_t*)(out + ((size_t)tile * 16 + t) * 2) = o;
            }
        }
    }
}

extern "C" void kernel_launch(void* const* d_in, const int* in_sizes, int n_in,
                              void* d_out, int out_size, void* d_ws, size_t ws_size,
                              hipStream_t stream) {
    const float* x   = (const float*)d_in[0];
    const float* W1  = (const float*)d_in[1];
    const float* b1  = (const float*)d_in[2];
    const float* W2  = (const float*)d_in[3];
    const float* b2  = (const float*)d_in[4];
    const float* W3  = (const float*)d_in[5];
    const float* b3  = (const float*)d_in[6];
    const float* Wg1 = (const float*)d_in[7];
    const float* bg1 = (const float*)d_in[8];
    const float* Wg2 = (const float*)d_in[9];
    const float* bg2 = (const float*)d_in[10];
    float* out = (float*)d_out;

    const int B      = in_sizes[0] / DIN_;
    const int nTiles = (B + 15) / 16;
    // waves_per_eu(2,2): arch 128 + acc 128 per wave; arch demand ~100 -> zero spills.
    // 512 blocks x 4 waves = 2048 waves = exact 2-wave/SIMD fill (2 blocks/CU, 64 KB LDS/CU).
    // nTiles (65536) / 2048 = 32 tiles/wave = 8 quad-iterations, zero tail.
    const int blocks = 512;
    const int wavesTotal = blocks * 4;
    const int tpw = (nTiles + wavesTotal - 1) / wavesTotal;

    moe_kernel<<<blocks, 256, 0, stream>>>(x, W1, b1, W2, b2, W3, b3,
                                           Wg1, bg1, Wg2, bg2, out, nTiles, tpw);
}

// Round 7
// 129.207 us; speedup vs baseline: 1.4124x; 1.0410x over previous
//
#include <hip/hip_runtime.h>

// MoE: out[b,:] = sum_e softmax(gate(x))[b,e] * (W3_e^T @ relu(W2_e^T @ relu(W1_e^T @ x_b + b1) + b2) + b3)
// Tokens-as-N MFMA. L1 uses 16x16x16 f16 (K=7 useful, k=4q+j). L2/L3/gate-L2 use 16x16x32 f16
// with K-permutation pi(q*8+j)=q*4+(j&3)+16*(j>>2) so C/D layout == next layer's B layout
// in-lane (HW-verified across R2-R14: absmax 0.0156).
// R15: "fit 3 waves/SIMD" package. Evidence: R12->R13 (1->2 waves) scaled 1.95x; R13->R14
//      (2x->4x intra-wave ILP) gave +3% -- TLP is the lever, ILP is exhausted. Register model
//      (4-for-4 across R9-R14): arch cap = wave-budget/2, so waves_per_eu(3,3) -> cap ~84.
//      To fit from R14's 88: (a) TB back to 2 (R14 proved TB4~TB2, -14 steady regs);
//      (b) G1/G2/W3S -> per-lane LDS images (wave0 builds; volatile re-read per iteration so
//          they can't be hoisted into persistent regs): -12;
//      (c) b2 -> f32 C-init of the L2 MFMA from a broadcast LDS table b2f32[e][m] (rows
//          m=4q+r match the verified C/D layout): -32 VALU/tile (-15%), -1 loop reg, kills
//          b2img, and adds bias in f32 pre-pack (better precision).
//      768 blocks x 4 waves = 3072 waves = exact 3 blocks/CU; 28 KB LDS x 3 = 84 KB/CU.
//      Falsifiable: WRITE_SIZE must stay 8.19 MB (no spills); else revert occupancy.

typedef _Float16 half2_t __attribute__((ext_vector_type(2)));
typedef _Float16 half4_t __attribute__((ext_vector_type(4)));
typedef _Float16 half8_t __attribute__((ext_vector_type(8)));
typedef __fp16   fp16v2  __attribute__((ext_vector_type(2)));
typedef float  float4_t __attribute__((ext_vector_type(4)));
typedef float  float2_t __attribute__((ext_vector_type(2)));
typedef int    int2_t   __attribute__((ext_vector_type(2)));
typedef int    int4_t   __attribute__((ext_vector_type(4)));

#define MFMA_K32(A, B, C) __builtin_amdgcn_mfma_f32_16x16x32_f16((A), (B), (C), 0, 0, 0)
#define MFMA_K16(A, B, C) __builtin_amdgcn_mfma_f32_16x16x16f16((A), (B), (C), 0, 0, 0)

static constexpr int E_ = 8, DIN_ = 6, H_ = 32, TB_ = 2;   // tiles per iteration

union H8U { half2_t h2[4]; half8_t h8; int4_t i4; };
union H4U { half2_t h2[2]; half4_t h4; int2_t i2; };
union W1U { H4U f[2]; int4_t i4; };    // 16B: both L1 A-fragments (or both gate-L1 frags)
union HI  { half2_t h; int i; };
union PKU { fp16v2 p; half2_t h; };

__device__ __forceinline__ half2_t pkrtz(float a, float b) {
    PKU u; u.p = __builtin_amdgcn_cvt_pkrtz(a, b);
    return u.h;
}

__device__ __forceinline__ half2_t relu2(half2_t v) {
    const half2_t z = {(_Float16)0.0f, (_Float16)0.0f};
    return __builtin_elementwise_max(v, z);
}

// full gate chain for one tile: logits (log2 domain) -> ex weights for this lane's expert
// pair {2q,2q+1} + deferred-normalization reciprocal (valid in quads 0-1)
__device__ __forceinline__ void gate_eval(
    half4_t xB, const H4U* G1, const H8U& G2, float4_t bg2F, float4_t zero4,
    int gsrc, int q, float& ga, float& gb, float& rs)
{
    float4_t hgLo = MFMA_K16(G1[0].h4, xB, zero4);
    float4_t hgHi = MFMA_K16(G1[1].h4, xB, zero4);
    H8U uh;
    uh.h2[0] = relu2(pkrtz(hgLo[0], hgLo[1]));
    uh.h2[1] = relu2(pkrtz(hgLo[2], hgLo[3]));
    uh.h2[2] = relu2(pkrtz(hgHi[0], hgHi[1]));
    uh.h2[3] = relu2(pkrtz(hgHi[2], hgHi[3]));
    float4_t gl = MFMA_K32(G2.h8, uh.h8, bg2F);
    float ex0 = __builtin_amdgcn_exp2f(gl[0]);
    float ex1 = __builtin_amdgcn_exp2f(gl[1]);
    float ex2 = __builtin_amdgcn_exp2f(gl[2]);
    float ex3 = __builtin_amdgcn_exp2f(gl[3]);
    float s = (ex0 + ex1) + (ex2 + ex3);
    s += __shfl_xor(s, 16);
    rs = __builtin_amdgcn_rcpf(s);
    HI pa, pb;
    pa.h = pkrtz(ex0, ex1);
    pb.h = pkrtz(ex2, ex3);
    int va = __builtin_amdgcn_ds_bpermute(gsrc, pa.i);
    int vb = __builtin_amdgcn_ds_bpermute(gsrc, pb.i);
    HI gsel; gsel.i = (q & 1) ? vb : va;   // lane(q,t): ex[t,2q], ex[t,2q+1]
    ga = (float)gsel.h[0];
    gb = (float)gsel.h[1];
}

__global__ __launch_bounds__(256)
__attribute__((amdgpu_waves_per_eu(3, 3)))
void moe_kernel(
    const float* __restrict__ x,  const float* __restrict__ W1, const float* __restrict__ b1,
    const float* __restrict__ W2, const float* __restrict__ b2, const float* __restrict__ W3,
    const float* __restrict__ b3, const float* __restrict__ Wg1, const float* __restrict__ bg1,
    const float* __restrict__ Wg2, const float* __restrict__ bg2,
    float* __restrict__ out, int nTiles, int tilesPerWave)
{
    const int tid  = threadIdx.x;
    const int lane = tid & 63;
    const int t    = lane & 15;   // token slot
    const int q    = lane >> 4;   // K-quad / row-quad
    const int wv   = tid >> 6;    // wave in block
    const int gw   = (blockIdx.x << 2) + wv;   // global wave id (waves independent in loop)
    const int eo   = t >> 1;      // the ONE expert whose L3 rows this lane holds

    // block-uniform images (every wave reads the same fragments)
    __shared__ W1U  w1img[E_][64];        //  8 KB: [e][lane] -> both L1 A-fragments
    __shared__ H8U  w2img[E_][2][64];     // 16 KB: [e][half][lane] -> L2 A-fragment
    __shared__ float b2f32[E_][H_];       //  1 KB: b2 rows (f32 C-init, broadcast reads)
    __shared__ W1U  g1img[64];            //  1 KB: per-lane gate-L1 fragments
    __shared__ H8U  g2img[64];            //  1 KB: per-lane gate-L2 fragment
    __shared__ H8U  w3img[64];            //  1 KB: per-lane sparse W3 fragment (expert eo)

    const float L2E = 1.44269504f;

    // ---- build expert images: wave wv packs experts {2wv, 2wv+1} (pi layout as R2-R14)
    #pragma unroll
    for (int j = 0; j < 2; ++j) {
        const int e = wv * 2 + j;
        W1U w1v;
        #pragma unroll
        for (int f = 0; f < 2; ++f) {
            float v0 = 0.f, v1 = 0.f, v2 = 0.f, v3 = 0.f;
            const float* We = W1 + (size_t)e * DIN_ * H_ + f * 16 + t;
            if (q == 0)      { v0 = We[0 * H_]; v1 = We[1 * H_]; v2 = We[2 * H_]; v3 = We[3 * H_]; }
            else if (q == 1) { v0 = We[4 * H_]; v1 = We[5 * H_]; v2 = b1[e * H_ + f * 16 + t]; }
            w1v.f[f].h2[0] = pkrtz(v0, v1); w1v.f[f].h2[1] = pkrtz(v2, v3);
        }
        w1img[e][lane] = w1v;
        H8U w2lo, w2hi;
        #pragma unroll
        for (int p = 0; p < 4; ++p) {
            int c0 = ((p >> 1) << 4) + q * 4 + ((p & 1) << 1);
            w2lo.h2[p] = pkrtz(W2[(e * H_ + c0) * H_ + 0  + t], W2[(e * H_ + c0 + 1) * H_ + 0  + t]);
            w2hi.h2[p] = pkrtz(W2[(e * H_ + c0) * H_ + 16 + t], W2[(e * H_ + c0 + 1) * H_ + 16 + t]);
        }
        w2img[e][0][lane] = w2lo;
        w2img[e][1][lane] = w2hi;
        if (lane < H_) b2f32[e][lane] = b2[e * H_ + lane];   // f32 C-init rows
    }

    // ---- wave 0 builds the per-lane gate + W3 images (lane-determined, identical all waves)
    if (wv == 0) {
        W1U g1v;
        #pragma unroll
        for (int f = 0; f < 2; ++f) {
            float v0 = 0.f, v1 = 0.f, v2 = 0.f, v3 = 0.f;
            if (q == 0) {
                v0 = Wg1[0 * H_ + f * 16 + t]; v1 = Wg1[1 * H_ + f * 16 + t];
                v2 = Wg1[2 * H_ + f * 16 + t]; v3 = Wg1[3 * H_ + f * 16 + t];
            } else if (q == 1) {
                v0 = Wg1[4 * H_ + f * 16 + t]; v1 = Wg1[5 * H_ + f * 16 + t];
                v2 = bg1[f * 16 + t];          v3 = 0.f;
            }
            g1v.f[f].h2[0] = pkrtz(v0, v1); g1v.f[f].h2[1] = pkrtz(v2, v3);
        }
        g1img[lane] = g1v;
        H8U g2v, w3v;
        #pragma unroll
        for (int p = 0; p < 4; ++p) {
            int c0 = ((p >> 1) << 4) + q * 4 + ((p & 1) << 1);
            float v0 = (t < E_) ? Wg2[c0 * E_ + t] * L2E : 0.f;
            float v1 = (t < E_) ? Wg2[(c0 + 1) * E_ + t] * L2E : 0.f;
            g2v.h2[p] = pkrtz(v0, v1);
            w3v.h2[p] = pkrtz(W3[(eo * H_ + c0) * 2 + (t & 1)],
                              W3[(eo * H_ + c0 + 1) * 2 + (t & 1)]);
        }
        g2img[lane] = g2v;
        w3img[lane] = w3v;
    }

    // ---- persistent C-inits: bg2 (log2 domain), b3 for all 16 Y rows m=(e,o)
    float4_t bg2F, b3F;
    #pragma unroll
    for (int r = 0; r < 4; ++r) {
        int m = q * 4 + r;
        bg2F[r] = (m < E_) ? bg2[m] * L2E : 0.f;
        b3F[r]  = b3[m];
    }
    const float4_t zero4 = {0.f, 0.f, 0.f, 0.f};
    const int4_t  zeroi  = {0, 0, 0, 0};

    // gate pull: lane(q,t) fetches ex[t,2q],ex[t,2q+1] from lane (q>>1)*16+t
    const int gsrc = ((((q >> 1) << 4) | t) << 2);

    __syncthreads();   // images ready; NO barriers inside the loop

    const int tile0 = gw * tilesPerWave;

    // ---- per-lane x source: quad0 reads x[t][0..3]; quads>=1 read x[t][4..5]
    const int xo1 = (q == 0) ? 0 : 4;
    const int xo2 = (q == 0) ? 2 : 4;
    const float* xq = x + ((size_t)tile0 * 16 + t) * DIN_;
    float2_t la[TB_], lb[TB_];
    #pragma unroll
    for (int u = 0; u < TB_; ++u) {
        la[u] = float2_t{0.f, 0.f};
        lb[u] = float2_t{0.f, 0.f};
        if (tile0 + u < nTiles) {
            la[u] = *(const float2_t*)(xq + (size_t)u * 16 * DIN_ + xo1);
            lb[u] = *(const float2_t*)(xq + (size_t)u * 16 * DIN_ + xo2);
        }
    }

    HI onei; onei.h = pkrtz(1.f, 0.f);
    const bool isq0 = (q == 0);

    // ---- main loop: two tiles per iteration
    for (int it = 0; it < tilesPerWave; it += TB_) {
        const int tb = tile0 + it;
        if (tb >= nTiles) break;            // uniform per wave

        // re-read per-lane images each iteration (volatile: must NOT be hoisted to
        // persistent registers -- that would blow the 3-wave arch budget)
        W1U g1v; g1v.i4 = *(const volatile int4_t*)&g1img[lane].i4;
        H8U g2v; g2v.i4 = *(const volatile int4_t*)&g2img[lane].i4;
        H8U w3v; w3v.i4 = *(const volatile int4_t*)&w3img[lane].i4;

        // x B-fragments (K=16): q0:(x0..x3) q1:(x4,x5,1,dc) q2/q3: dc (A=0 there)
        H4U ux[TB_];
        #pragma unroll
        for (int u = 0; u < TB_; ++u) {
            ux[u].h2[0] = pkrtz(la[u][0], la[u][1]);
            HI hb; hb.h = pkrtz(lb[u][0], lb[u][1]);
            HI se; se.i = isq0 ? hb.i : onei.i;
            ux[u].h2[1] = se.h;
        }

        // prefetch next pair's x
        if (it + TB_ < tilesPerWave) {
            const float* xn = xq + (size_t)(it + TB_) * 16 * DIN_;
            #pragma unroll
            for (int u = 0; u < TB_; ++u) {
                if (tb + TB_ + u < nTiles) {
                    la[u] = *(const float2_t*)(xn + (size_t)u * 16 * DIN_ + xo1);
                    lb[u] = *(const float2_t*)(xn + (size_t)u * 16 * DIN_ + xo2);
                }
            }
        }

        // gates (once per tile; two independent chains)
        float ga[TB_], gb[TB_], rs[TB_];
        #pragma unroll
        for (int u = 0; u < TB_; ++u)
            gate_eval(ux[u].h4, g1v.f, g2v, bg2F, zero4, gsrc, q, ga[u], gb[u], rs[u]);

        // all 8 experts x 2 tiles; weights from LDS once per expert; b2 via f32 C-init
        float4_t Ya[TB_], Yb[TB_];
        #pragma unroll
        for (int u = 0; u < TB_; ++u) { Ya[u] = b3F; Yb[u] = zero4; }
        #pragma unroll
        for (int e = 0; e < E_; ++e) {
            W1U w1v  = w1img[e][lane];
            H8U w2lo = w2img[e][0][lane];
            H8U w2hi = w2img[e][1][lane];
            float4_t b2clo = *(const float4_t*)&b2f32[e][q * 4];        // rows m=4q+r
            float4_t b2chi = *(const float4_t*)&b2f32[e][16 + q * 4];   // rows m=16+4q+r
            H8U a3;  a3.i4 = (eo == e) ? w3v.i4 : zeroi;   // sparse L3 rows: mask per expert

            #pragma unroll
            for (int u = 0; u < TB_; ++u) {
                float4_t lo = MFMA_K16(w1v.f[0].h4, ux[u].h4, zero4);
                float4_t hi = MFMA_K16(w1v.f[1].h4, ux[u].h4, zero4);
                H8U u1;
                u1.h2[0] = relu2(pkrtz(lo[0], lo[1]));
                u1.h2[1] = relu2(pkrtz(lo[2], lo[3]));
                u1.h2[2] = relu2(pkrtz(hi[0], hi[1]));
                u1.h2[3] = relu2(pkrtz(hi[2], hi[3]));
                float4_t lo2 = MFMA_K32(w2lo.h8, u1.h8, b2clo);   // bias in f32 C-init
                float4_t hi2 = MFMA_K32(w2hi.h8, u1.h8, b2chi);
                H8U u2;
                u2.h2[0] = relu2(pkrtz(lo2[0], lo2[1]));
                u2.h2[1] = relu2(pkrtz(lo2[2], lo2[3]));
                u2.h2[2] = relu2(pkrtz(hi2[0], hi2[1]));
                u2.h2[3] = relu2(pkrtz(hi2[2], hi2[3]));
                if (e & 1) Yb[u] = MFMA_K32(a3.h8, u2.h8, Yb[u]);
                else       Ya[u] = MFMA_K32(a3.h8, u2.h8, Ya[u]);
            }
        }

        // epilogues: lane(q,t) holds Y rows m=4q+r -> experts {2q,2q+1}, o=r&1
        #pragma unroll
        for (int u = 0; u < TB_; ++u) {
            const int tile = tb + u;
            float p0 = ga[u] * (Ya[u][0] + Yb[u][0]) + gb[u] * (Ya[u][2] + Yb[u][2]);
            float p1 = ga[u] * (Ya[u][1] + Yb[u][1]) + gb[u] * (Ya[u][3] + Yb[u][3]);
            p0 += __shfl_xor(p0, 16);
            p0 += __shfl_xor(p0, 32);
            p1 += __shfl_xor(p1, 16);
            p1 += __shfl_xor(p1, 32);
            if (tile < nTiles && lane < 16) {
                float2_t o = {p0 * rs[u], p1 * rs[u]};
                *(float2_t*)(out + ((size_t)tile * 16 + t) * 2) = o;
            }
        }
    }
}

extern "C" void kernel_launch(void* const* d_in, const int* in_sizes, int n_in,
                              void* d_out, int out_size, void* d_ws, size_t ws_size,
                              hipStream_t stream) {
    const float* x   = (const float*)d_in[0];
    const float* W1  = (const float*)d_in[1];
    const float* b1  = (const float*)d_in[2];
    const float* W2  = (const float*)d_in[3];
    const float* b2  = (const float*)d_in[4];
    const float* W3  = (const float*)d_in[5];
    const float* b3  = (const float*)d_in[6];
    const float* Wg1 = (const float*)d_in[7];
    const float* bg1 = (const float*)d_in[8];
    const float* Wg2 = (const float*)d_in[9];
    const float* bg2 = (const float*)d_in[10];
    float* out = (float*)d_out;

    const int B      = in_sizes[0] / DIN_;
    const int nTiles = (B + 15) / 16;
    // waves_per_eu(3,3): arch ~84 + acc ~84 per wave; arch demand ~76-80 -> zero spills.
    // 768 blocks x 4 waves = 3072 waves = exact 3 blocks/CU (12 waves/CU), 84 KB LDS/CU.
    // tpw = ceil(65536/3072) = 22; ragged tail handled by per-tile guards.
    const int blocks = 768;
    const int wavesTotal = blocks * 4;
    const int tpw = (nTiles + wavesTotal - 1) / wavesTotal;

    moe_kernel<<<blocks, 256, 0, stream>>>(x, W1, b1, W2, b2, W3, b3,
                                           Wg1, bg1, Wg2, bg2, out, nTiles, tpw);
}